// Round 1
// baseline (1304.780 us; speedup 1.0000x reference)
//
#include <hip/hip_runtime.h>
#include <math.h>

#define BB 4
#define CDIM 256
#define NN 2048
#define HEADS 8
#define DH 64
#define HIDDEN 512
#define THREEH 1536
#define SCALE 0.125f

// ---------------- Kernel A: qkv[b][o][n] = sum_c w_qkv[o][c] * x[b][c][n] ----------------
// 64x64 output tile per block, 256 threads, 4x4 micro-tile per thread.
__global__ __launch_bounds__(256) void qkv_gemm(const float* __restrict__ x,
                                                const float* __restrict__ w,
                                                float* __restrict__ qkv) {
    __shared__ float Ws[64][66];   // [o][c], pad 66 keeps float2 aligned, 2-way bank = free
    __shared__ float Xs[64][66];   // [n][c] (transposed on store)
    const int n0 = blockIdx.x * 64, o0 = blockIdx.y * 64, b = blockIdx.z;
    const int t = threadIdx.x, lane = t & 63, wv = t >> 6;
    const int i2 = lane >> 4, m2 = lane & 15;
    float acc[4][4] = {};
    const float* xb = x + (size_t)b * CDIM * NN;
    for (int kc = 0; kc < CDIM; kc += 64) {
        __syncthreads();
        {
            const int c = lane;
            for (int s = 0; s < 16; ++s) {
                const int o = wv + 4 * s;
                Ws[o][c] = w[(size_t)(o0 + o) * CDIM + kc + c];
            }
            const int n = lane;
            for (int s = 0; s < 16; ++s) {
                const int cr = wv + 4 * s;
                Xs[n][cr] = xb[(size_t)(kc + cr) * NN + n0 + n];
            }
        }
        __syncthreads();
        for (int cc = 0; cc < 64; cc += 2) {
            float2 wr[4], xr[4];
            for (int a = 0; a < 4; ++a) wr[a] = *(const float2*)&Ws[wv * 16 + i2 * 4 + a][cc];
            for (int bb = 0; bb < 4; ++bb) xr[bb] = *(const float2*)&Xs[m2 * 4 + bb][cc];
            for (int a = 0; a < 4; ++a)
                for (int bb = 0; bb < 4; ++bb)
                    acc[a][bb] += wr[a].x * xr[bb].x + wr[a].y * xr[bb].y;
        }
    }
    for (int a = 0; a < 4; ++a) {
        const int o = o0 + wv * 16 + i2 * 4 + a;
        float4 r = make_float4(acc[a][0], acc[a][1], acc[a][2], acc[a][3]);
        *(float4*)&qkv[((size_t)b * THREEH + o) * NN + n0 + m2 * 4] = r;
    }
}

// ---------------- Kernel B: flash attention per (b,h,q-tile) ----------------
// Block = 256 threads = 4 waves; each wave owns 16 query rows.
// Thread (wave w, lane): rows q = w*16 + (lane>>4)*4 + a, cols = (lane&15)*4 + b.
// Row-wise softmax reductions stay within each 16-lane group (shfl_xor 1,2,4,8).
__global__ __launch_bounds__(256) void flash_attn(const float* __restrict__ qkv,
                                                  float* __restrict__ Y) {
    __shared__ float Qs[64][66];   // [q][c], pre-scaled
    __shared__ float KP[64][66];   // K as [m][c]; reused as P[q][m]
    __shared__ float Vt[64][66];   // V as [c][m]
    const int q0 = blockIdx.x * 64;
    const int h = blockIdx.y, b = blockIdx.z;
    const int t = threadIdx.x, lane = t & 63, w = t >> 6;
    const int i2 = lane >> 4, m2 = lane & 15;
    const float* qbase = qkv + ((size_t)b * THREEH + h * DH) * NN;
    const float* kbase = qbase + (size_t)HIDDEN * NN;
    const float* vbase = qbase + (size_t)2 * HIDDEN * NN;
    {
        const int q = lane;
        for (int s = 0; s < 16; ++s) {
            const int c = w + 4 * s;
            Qs[q][c] = qbase[(size_t)c * NN + q0 + q] * SCALE;
        }
    }
    float m_i[4], l_i[4], O[4][4] = {};
    for (int a = 0; a < 4; ++a) { m_i[a] = -INFINITY; l_i[a] = 0.f; }
    __syncthreads();

    for (int m0 = 0; m0 < NN; m0 += 64) {
        {   // stage K and V tiles
            const int m = lane;
            for (int s = 0; s < 16; ++s) {
                const int c = w + 4 * s;
                KP[m][c] = kbase[(size_t)c * NN + m0 + m];
                Vt[c][m] = vbase[(size_t)c * NN + m0 + m];
            }
        }
        __syncthreads();
        // S = Q K^T (4x4 per thread)
        float sv[4][4] = {};
        for (int cc = 0; cc < 64; cc += 2) {
            float2 qv[4], kv[4];
            for (int a = 0; a < 4; ++a) qv[a] = *(const float2*)&Qs[w * 16 + i2 * 4 + a][cc];
            for (int bb = 0; bb < 4; ++bb) kv[bb] = *(const float2*)&KP[m2 * 4 + bb][cc];
            for (int a = 0; a < 4; ++a)
                for (int bb = 0; bb < 4; ++bb)
                    sv[a][bb] += qv[a].x * kv[bb].x + qv[a].y * kv[bb].y;
        }
        // online softmax
        float p[4][4];
        for (int a = 0; a < 4; ++a) {
            float rm = fmaxf(fmaxf(sv[a][0], sv[a][1]), fmaxf(sv[a][2], sv[a][3]));
            for (int off = 1; off < 16; off <<= 1) rm = fmaxf(rm, __shfl_xor(rm, off));
            const float mn = fmaxf(m_i[a], rm);
            const float alpha = __expf(m_i[a] - mn);
            m_i[a] = mn;
            float lsum = 0.f;
            for (int bb = 0; bb < 4; ++bb) { p[a][bb] = __expf(sv[a][bb] - mn); lsum += p[a][bb]; }
            for (int off = 1; off < 16; off <<= 1) lsum += __shfl_xor(lsum, off);
            l_i[a] = l_i[a] * alpha + lsum;
            for (int bb = 0; bb < 4; ++bb) O[a][bb] *= alpha;
        }
        __syncthreads();   // all waves done reading K
        for (int a = 0; a < 4; ++a) {
            *(float2*)&KP[w * 16 + i2 * 4 + a][m2 * 4]     = make_float2(p[a][0], p[a][1]);
            *(float2*)&KP[w * 16 + i2 * 4 + a][m2 * 4 + 2] = make_float2(p[a][2], p[a][3]);
        }
        __syncthreads();
        // O += P V (cols c = m2*4+bb)
        for (int mm = 0; mm < 64; mm += 2) {
            float2 pv[4], vv[4];
            for (int a = 0; a < 4; ++a) pv[a] = *(const float2*)&KP[w * 16 + i2 * 4 + a][mm];
            for (int bb = 0; bb < 4; ++bb) vv[bb] = *(const float2*)&Vt[m2 * 4 + bb][mm];
            for (int a = 0; a < 4; ++a)
                for (int bb = 0; bb < 4; ++bb)
                    O[a][bb] += pv[a].x * vv[bb].x + pv[a].y * vv[bb].y;
        }
        __syncthreads();   // done with KP/Vt before next staging
    }
    // epilogue: normalize and store Y[b][q][h*64 + c]
    for (int a = 0; a < 4; ++a) {
        const float inv = 1.f / l_i[a];
        const int q = q0 + w * 16 + i2 * 4 + a;
        float4 r = make_float4(O[a][0] * inv, O[a][1] * inv, O[a][2] * inv, O[a][3] * inv);
        *(float4*)&Y[((size_t)b * NN + q) * HIDDEN + h * DH + m2 * 4] = r;
    }
}

// ---------------- Kernel C: out[b][o][n] = sum_k w_out[o][k] * Y[b][n][k] + b_out[o] ----------------
__global__ __launch_bounds__(256) void out_gemm(const float* __restrict__ Y,
                                                const float* __restrict__ w,
                                                const float* __restrict__ bias,
                                                float* __restrict__ out) {
    __shared__ float Ws[64][66];   // [o][k]
    __shared__ float Ys[64][66];   // [n][k]
    const int n0 = blockIdx.x * 64, o0 = blockIdx.y * 64, b = blockIdx.z;
    const int t = threadIdx.x, lane = t & 63, wv = t >> 6;
    const int i2 = lane >> 4, m2 = lane & 15;
    float acc[4][4] = {};
    const float* yb = Y + (size_t)b * NN * HIDDEN;
    for (int kc = 0; kc < HIDDEN; kc += 64) {
        __syncthreads();
        {
            const int k = lane;
            for (int s = 0; s < 16; ++s) {
                const int o = wv + 4 * s;
                Ws[o][k] = w[(size_t)(o0 + o) * HIDDEN + kc + k];
            }
            for (int s = 0; s < 16; ++s) {
                const int n = wv + 4 * s;
                Ys[n][k] = yb[(size_t)(n0 + n) * HIDDEN + kc + k];
            }
        }
        __syncthreads();
        for (int cc = 0; cc < 64; cc += 2) {
            float2 wr[4], yr[4];
            for (int a = 0; a < 4; ++a) wr[a] = *(const float2*)&Ws[wv * 16 + i2 * 4 + a][cc];
            for (int bb = 0; bb < 4; ++bb) yr[bb] = *(const float2*)&Ys[m2 * 4 + bb][cc];
            for (int a = 0; a < 4; ++a)
                for (int bb = 0; bb < 4; ++bb)
                    acc[a][bb] += wr[a].x * yr[bb].x + wr[a].y * yr[bb].y;
        }
    }
    for (int a = 0; a < 4; ++a) {
        const int o = o0 + wv * 16 + i2 * 4 + a;
        const float bv = bias[o];
        float4 r = make_float4(acc[a][0] + bv, acc[a][1] + bv, acc[a][2] + bv, acc[a][3] + bv);
        *(float4*)&out[((size_t)b * CDIM + o) * NN + n0 + m2 * 4] = r;
    }
}

extern "C" void kernel_launch(void* const* d_in, const int* in_sizes, int n_in,
                              void* d_out, int out_size, void* d_ws, size_t ws_size,
                              hipStream_t stream) {
    const float* x     = (const float*)d_in[0];
    const float* w_qkv = (const float*)d_in[1];
    const float* w_out = (const float*)d_in[2];
    const float* b_out = (const float*)d_in[3];
    float* out = (float*)d_out;
    float* qkv = (float*)d_ws;                           // 4*1536*2048 floats = 48 MiB
    float* Y   = qkv + (size_t)BB * THREEH * NN;         // 4*2048*512 floats = 16 MiB

    qkv_gemm<<<dim3(NN / 64, THREEH / 64, BB), 256, 0, stream>>>(x, w_qkv, qkv);
    flash_attn<<<dim3(NN / 64, HEADS, BB), 256, 0, stream>>>(qkv, Y);
    out_gemm<<<dim3(NN / 64, CDIM / 64, BB), 256, 0, stream>>>(Y, w_out, b_out, out);
}

// Round 2
// 239.631 us; speedup vs baseline: 5.4449x; 5.4449x over previous
//
#include <hip/hip_runtime.h>
#include <math.h>

#define BB 4
#define CDIM 256
#define NN 2048
#define HEADS 8
#define DH 64
#define HIDDEN 512
#define THREEH 1536
#define SCALE 0.125f

typedef __attribute__((ext_vector_type(8))) short bf16x8;
typedef __attribute__((ext_vector_type(4))) float f32x4;

static __device__ inline unsigned short f2bf(float f) {
    unsigned u = __float_as_uint(f);
    u += 0x7fff + ((u >> 16) & 1);   // round-to-nearest-even
    return (unsigned short)(u >> 16);
}
static __device__ inline unsigned pk2(float a, float b) {
    return (unsigned)f2bf(a) | ((unsigned)f2bf(b) << 16);
}
#define MFMA16(a, b, c) __builtin_amdgcn_mfma_f32_16x16x32_bf16(a, b, c, 0, 0, 0)

// ---------------- Kernel A: qkv^T tile GEMM ----------------
// D[n][o] = sum_c x^T[n][c] * w^T[c][o]  => D = qkv^T tile; store transposed.
// A-frag (left) rows n: needs Xs[n][c] c-contiguous (transpose-staged).
// B-frag (right) cols o: needs Ws[o][c] c-contiguous (natural layout of w).
__global__ __launch_bounds__(256, 4) void qkv_gemm(const float* __restrict__ x,
                                                   const float* __restrict__ w,
                                                   float* __restrict__ qkv) {
    __shared__ unsigned short Xs[64][72];
    __shared__ unsigned short Ws[64][72];
    const int n0 = blockIdx.x * 64, o0 = blockIdx.y * 64, b = blockIdx.z;
    const int t = threadIdx.x, l = t & 63, w4 = t >> 6, lo = l & 15, quad = l >> 4;
    const float* xb = x + (size_t)b * CDIM * NN;
    f32x4 acc[4];
#pragma unroll
    for (int i = 0; i < 4; ++i) acc[i] = (f32x4){0.f, 0.f, 0.f, 0.f};
    for (int kc = 0; kc < CDIM; kc += 64) {
        __syncthreads();
        {   // X transpose-stage: Xs[n][c] = x[kc+c][n0+n]
            const int c4 = quad + 4 * w4;
#pragma unroll
            for (int s = 0; s < 4; ++s) {
                const int n = lo + 16 * s;
                const float* p = &xb[(size_t)(kc + c4 * 4) * NN + n0 + n];
                uint2 u;
                u.x = pk2(p[0], p[NN]);
                u.y = pk2(p[2 * NN], p[3 * NN]);
                *(uint2*)&Xs[n][c4 * 4] = u;
            }
        }
#pragma unroll
        for (int s = 0; s < 4; ++s) {   // W natural stage: Ws[o][c] = w[o0+o][kc+c]
            const int chunk = t + 256 * s;
            const int o = chunk >> 4, k4 = chunk & 15;
            float4 v = *(const float4*)&w[(size_t)(o0 + o) * CDIM + kc + k4 * 4];
            uint2 u;
            u.x = pk2(v.x, v.y);
            u.y = pk2(v.z, v.w);
            *(uint2*)&Ws[o][k4 * 4] = u;
        }
        __syncthreads();
        bf16x8 a0 = *(const bf16x8*)&Xs[16 * w4 + lo][quad * 8];
        bf16x8 a1 = *(const bf16x8*)&Xs[16 * w4 + lo][32 + quad * 8];
#pragma unroll
        for (int ot = 0; ot < 4; ++ot) {
            bf16x8 b0 = *(const bf16x8*)&Ws[ot * 16 + lo][quad * 8];
            bf16x8 b1 = *(const bf16x8*)&Ws[ot * 16 + lo][32 + quad * 8];
            acc[ot] = MFMA16(a0, b0, acc[ot]);
            acc[ot] = MFMA16(a1, b1, acc[ot]);
        }
    }
    const int nbase = n0 + 16 * w4 + quad * 4;   // D rows = n (quad*4+reg)
#pragma unroll
    for (int ot = 0; ot < 4; ++ot) {
        const int o = o0 + ot * 16 + lo;         // D cols = o (lane&15)
        *(f32x4*)&qkv[((size_t)b * THREEH + o) * NN + nbase] = acc[ot];
    }
}

// ---------------- Kernel B: MFMA flash attention ----------------
// S[q][m] = Q*K^T via A=Qs[q][c], B=Ks[m][c] (both c-contig).
// O^T[c][q] += V^T * P^T via A=Vs[c][m] (natural!), B=Ps[q][m].
__global__ __launch_bounds__(256, 4) void flash_attn(const float* __restrict__ qkv,
                                                     float* __restrict__ Y) {
    __shared__ unsigned short Qs[64][72], Ks[64][72], Vs[64][72], Ps[64][72];
    __shared__ float aL[4][16], lL[4][16];
    const int q0 = blockIdx.x * 64, h = blockIdx.y, b = blockIdx.z;
    const int t = threadIdx.x, l = t & 63, w = t >> 6, lo = l & 15, quad = l >> 4;
    const float* qb = qkv + ((size_t)b * THREEH + h * DH) * NN;
    const float* kb = qb + (size_t)HIDDEN * NN;
    const float* vb = qb + (size_t)2 * HIDDEN * NN;
    {   // stage Q transposed + scaled: Qs[q][c] = q[c][q0+q]*SCALE
        const int c4 = quad + 4 * w;
#pragma unroll
        for (int s = 0; s < 4; ++s) {
            const int q = lo + 16 * s;
            const float* p = &qb[(size_t)(c4 * 4) * NN + q0 + q];
            uint2 u;
            u.x = pk2(p[0] * SCALE, p[NN] * SCALE);
            u.y = pk2(p[2 * NN] * SCALE, p[3 * NN] * SCALE);
            *(uint2*)&Qs[q][c4 * 4] = u;
        }
    }
    __syncthreads();
    const bf16x8 aQ0 = *(const bf16x8*)&Qs[16 * w + lo][quad * 8];
    const bf16x8 aQ1 = *(const bf16x8*)&Qs[16 * w + lo][32 + quad * 8];
    f32x4 Oacc[4];
#pragma unroll
    for (int i = 0; i < 4; ++i) Oacc[i] = (f32x4){0.f, 0.f, 0.f, 0.f};
    float m_i[4], l_i[4];
#pragma unroll
    for (int r = 0; r < 4; ++r) { m_i[r] = -INFINITY; l_i[r] = 0.f; }

    for (int m0 = 0; m0 < NN; m0 += 64) {
        __syncthreads();   // prior iteration's Ks/Vs reads complete
        {   // K transpose-stage: Ks[m][c] = k[c][m0+m]
            const int c4 = quad + 4 * w;
#pragma unroll
            for (int s = 0; s < 4; ++s) {
                const int m = lo + 16 * s;
                const float* p = &kb[(size_t)(c4 * 4) * NN + m0 + m];
                uint2 u;
                u.x = pk2(p[0], p[NN]);
                u.y = pk2(p[2 * NN], p[3 * NN]);
                *(uint2*)&Ks[m][c4 * 4] = u;
            }
        }
#pragma unroll
        for (int s = 0; s < 4; ++s) {   // V natural stage: Vs[c][m] = v[c][m0+m]
            const int chunk = t + 256 * s;
            const int c = chunk >> 4, mc = chunk & 15;
            float4 v = *(const float4*)&vb[(size_t)c * NN + m0 + mc * 4];
            uint2 u;
            u.x = pk2(v.x, v.y);
            u.y = pk2(v.z, v.w);
            *(uint2*)&Vs[c][mc * 4] = u;
        }
        __syncthreads();
        // ---- S = Q K^T : per-wave 16q x 64m, C-layout row=quad*4+r, col=lo ----
        f32x4 S[4];
#pragma unroll
        for (int nt = 0; nt < 4; ++nt) {
            bf16x8 b0 = *(const bf16x8*)&Ks[nt * 16 + lo][quad * 8];
            bf16x8 b1 = *(const bf16x8*)&Ks[nt * 16 + lo][32 + quad * 8];
            f32x4 z = (f32x4){0.f, 0.f, 0.f, 0.f};
            z = MFMA16(aQ0, b0, z);
            z = MFMA16(aQ1, b1, z);
            S[nt] = z;
        }
        // ---- online softmax (rows live across the 16-lane group) ----
        float p4[4][4], alpha[4];
#pragma unroll
        for (int r = 0; r < 4; ++r) {
            float rm = fmaxf(fmaxf(S[0][r], S[1][r]), fmaxf(S[2][r], S[3][r]));
#pragma unroll
            for (int off = 1; off < 16; off <<= 1) rm = fmaxf(rm, __shfl_xor(rm, off));
            const float mn = fmaxf(m_i[r], rm);
            alpha[r] = __expf(m_i[r] - mn);
            m_i[r] = mn;
            float ls = 0.f;
#pragma unroll
            for (int nt = 0; nt < 4; ++nt) { p4[nt][r] = __expf(S[nt][r] - mn); ls += p4[nt][r]; }
#pragma unroll
            for (int off = 1; off < 16; off <<= 1) ls += __shfl_xor(ls, off);
            l_i[r] = l_i[r] * alpha[r] + ls;
        }
        // broadcast alpha per q-row through wave-private LDS slot
        if (lo == 0) *(float4*)&aL[w][quad * 4] = make_float4(alpha[0], alpha[1], alpha[2], alpha[3]);
        // P to LDS in A/B-friendly layout: Ps[q][m] (wave-private rows)
#pragma unroll
        for (int nt = 0; nt < 4; ++nt)
#pragma unroll
            for (int r = 0; r < 4; ++r)
                Ps[16 * w + quad * 4 + r][nt * 16 + lo] = f2bf(p4[nt][r]);
        const float av = aL[w][lo];   // alpha for this lane's O^T column q=lo
#pragma unroll
        for (int ct = 0; ct < 4; ++ct) Oacc[ct] *= av;
        // ---- O^T += V^T P^T ----
        bf16x8 pb0 = *(const bf16x8*)&Ps[16 * w + lo][quad * 8];
        bf16x8 pb1 = *(const bf16x8*)&Ps[16 * w + lo][32 + quad * 8];
#pragma unroll
        for (int ct = 0; ct < 4; ++ct) {
            bf16x8 a0 = *(const bf16x8*)&Vs[ct * 16 + lo][quad * 8];
            bf16x8 a1 = *(const bf16x8*)&Vs[ct * 16 + lo][32 + quad * 8];
            Oacc[ct] = MFMA16(a0, pb0, Oacc[ct]);
            Oacc[ct] = MFMA16(a1, pb1, Oacc[ct]);
        }
    }
    if (lo == 0) *(float4*)&lL[w][quad * 4] = make_float4(l_i[0], l_i[1], l_i[2], l_i[3]);
    const float inv = 1.f / lL[w][lo];
    const int q = q0 + 16 * w + lo;
#pragma unroll
    for (int ct = 0; ct < 4; ++ct) {   // O^T rows c = ct*16+quad*4+reg -> contiguous float4
        *(f32x4*)&Y[((size_t)b * NN + q) * HIDDEN + h * DH + ct * 16 + quad * 4] = Oacc[ct] * inv;
    }
}

// ---------------- Kernel C: out^T tile GEMM + bias ----------------
// D[n][o] = sum_k Y[n][k] * w_out[o][k]; both operands k-contiguous in memory.
__global__ __launch_bounds__(256, 4) void out_gemm(const float* __restrict__ Yin,
                                                   const float* __restrict__ w,
                                                   const float* __restrict__ bias,
                                                   float* __restrict__ out) {
    __shared__ unsigned short Ys[64][72], Ws[64][72];
    const int n0 = blockIdx.x * 64, o0 = blockIdx.y * 64, b = blockIdx.z;
    const int t = threadIdx.x, l = t & 63, w4 = t >> 6, lo = l & 15, quad = l >> 4;
    const float* yb = Yin + (size_t)b * NN * HIDDEN;
    f32x4 acc[4];
#pragma unroll
    for (int i = 0; i < 4; ++i) acc[i] = (f32x4){0.f, 0.f, 0.f, 0.f};
    for (int kc = 0; kc < HIDDEN; kc += 64) {
        __syncthreads();
#pragma unroll
        for (int s = 0; s < 4; ++s) {
            const int chunk = t + 256 * s;
            const int n = chunk >> 4, k4 = chunk & 15;
            float4 v = *(const float4*)&yb[(size_t)(n0 + n) * HIDDEN + kc + k4 * 4];
            uint2 u;
            u.x = pk2(v.x, v.y);
            u.y = pk2(v.z, v.w);
            *(uint2*)&Ys[n][k4 * 4] = u;
        }
#pragma unroll
        for (int s = 0; s < 4; ++s) {
            const int chunk = t + 256 * s;
            const int o = chunk >> 4, k4 = chunk & 15;
            float4 v = *(const float4*)&w[(size_t)(o0 + o) * HIDDEN + kc + k4 * 4];
            uint2 u;
            u.x = pk2(v.x, v.y);
            u.y = pk2(v.z, v.w);
            *(uint2*)&Ws[o][k4 * 4] = u;
        }
        __syncthreads();
        bf16x8 a0 = *(const bf16x8*)&Ys[16 * w4 + lo][quad * 8];
        bf16x8 a1 = *(const bf16x8*)&Ys[16 * w4 + lo][32 + quad * 8];
#pragma unroll
        for (int ot = 0; ot < 4; ++ot) {
            bf16x8 b0 = *(const bf16x8*)&Ws[ot * 16 + lo][quad * 8];
            bf16x8 b1 = *(const bf16x8*)&Ws[ot * 16 + lo][32 + quad * 8];
            acc[ot] = MFMA16(a0, b0, acc[ot]);
            acc[ot] = MFMA16(a1, b1, acc[ot]);
        }
    }
    const int nbase = n0 + 16 * w4 + quad * 4;
#pragma unroll
    for (int ot = 0; ot < 4; ++ot) {
        const int o = o0 + ot * 16 + lo;
        const float bv = bias[o];
        *(f32x4*)&out[((size_t)b * CDIM + o) * NN + nbase] = acc[ot] + bv;
    }
}

extern "C" void kernel_launch(void* const* d_in, const int* in_sizes, int n_in,
                              void* d_out, int out_size, void* d_ws, size_t ws_size,
                              hipStream_t stream) {
    const float* x     = (const float*)d_in[0];
    const float* w_qkv = (const float*)d_in[1];
    const float* w_out = (const float*)d_in[2];
    const float* b_out = (const float*)d_in[3];
    float* out = (float*)d_out;
    float* qkv = (float*)d_ws;                       // 4*1536*2048 f32 = 48 MiB
    float* Yw  = qkv + (size_t)BB * THREEH * NN;     // 4*2048*512  f32 = 16 MiB

    qkv_gemm<<<dim3(NN / 64, THREEH / 64, BB), 256, 0, stream>>>(x, w_qkv, qkv);
    flash_attn<<<dim3(NN / 64, HEADS, BB), 256, 0, stream>>>(qkv, Yw);
    out_gemm<<<dim3(NN / 64, CDIM / 64, BB), 256, 0, stream>>>(Yw, w_out, b_out, out);
}

// Round 3
// 199.558 us; speedup vs baseline: 6.5384x; 1.2008x over previous
//
#include <hip/hip_runtime.h>
#include <math.h>

#define BB 4
#define CDIM 256
#define NN 2048
#define HEADS 8
#define DH 64
#define HIDDEN 512
#define THREEH 1536
#define QSCALE 0.18033688011112042f   // 0.125 * log2(e): softmax done in exp2 domain

typedef __attribute__((ext_vector_type(8))) short bf16x8;
typedef __attribute__((ext_vector_type(4))) float f32x4;

static __device__ inline unsigned short f2bf(float f) {
    unsigned u = __float_as_uint(f);
    u += 0x7fff + ((u >> 16) & 1);
    return (unsigned short)(u >> 16);
}
#if __has_builtin(__builtin_amdgcn_cvt_pk_bf16_f32)
static __device__ inline unsigned pk2(float a, float b) {
    auto v = __builtin_amdgcn_cvt_pk_bf16_f32(a, b);
    return __builtin_bit_cast(unsigned, v);
}
#else
static __device__ inline unsigned pk2(float a, float b) {
    return (unsigned)f2bf(a) | ((unsigned)f2bf(b) << 16);
}
#endif
#if __has_builtin(__builtin_amdgcn_exp2f)
#define EXP2(x) __builtin_amdgcn_exp2f(x)
#else
#define EXP2(x) exp2f(x)
#endif
#define MFMA16(a, b, c) __builtin_amdgcn_mfma_f32_16x16x32_bf16(a, b, c, 0, 0, 0)

// ---------------- prep: fp32 weights -> bf16 (Q-rows of w_qkv pre-scaled) ----------------
__global__ __launch_bounds__(256) void prep_w(const float* __restrict__ wqkv,
                                              const float* __restrict__ wout,
                                              unsigned* __restrict__ Wqb,
                                              unsigned* __restrict__ Wob) {
    const int t = blockIdx.x * 256 + threadIdx.x;   // 131072 threads, 4 elems each
    if (t < 98304) {
        const int e = t * 4;
        const int o = e >> 8;                        // row of w_qkv (256 cols)
        const float s = (o < HIDDEN) ? QSCALE : 1.f;
        float4 v = *(const float4*)&wqkv[e];
        Wqb[t * 2 + 0] = pk2(v.x * s, v.y * s);
        Wqb[t * 2 + 1] = pk2(v.z * s, v.w * s);
    } else {
        const int e = (t - 98304) * 4;
        float4 v = *(const float4*)&wout[e];
        Wob[(t - 98304) * 2 + 0] = pk2(v.x, v.y);
        Wob[(t - 98304) * 2 + 1] = pk2(v.z, v.w);
    }
}

// ---------------- Kernel A: qkv projection, emits bf16 Q/K/V in attention-ready layouts ----------------
// Q/K blocks (o0 < 1024): D[o][n] (A=W, B=X^T) -> store [bh][n][c] (vector uint2 over c)
// V  blocks (o0 >= 1024): D[n][o] (A=X^T, B=W) -> store [bh][c][m] (vector uint2 over m)
__global__ __launch_bounds__(256, 4) void qkv_gemm(const float* __restrict__ x,
                                                   const unsigned short* __restrict__ Wqb,
                                                   unsigned short* __restrict__ Qb,
                                                   unsigned short* __restrict__ Kb,
                                                   unsigned short* __restrict__ Vb) {
    __shared__ unsigned short Xs[64][72];
    const int n0 = blockIdx.x * 64, o0 = blockIdx.y * 64, b = blockIdx.z;
    const int t = threadIdx.x, l = t & 63, w4 = t >> 6, lo = l & 15, quad = l >> 4;
    const float* xb = x + (size_t)b * CDIM * NN;
    const bool isV = (o0 >= 2 * HIDDEN);
    f32x4 acc[4];
#pragma unroll
    for (int i = 0; i < 4; ++i) acc[i] = (f32x4){0.f, 0.f, 0.f, 0.f};

    for (int kc = 0; kc < CDIM; kc += 64) {
        __syncthreads();
        {   // transpose-stage Xs[n][c] = x[kc+c][n0+n], bf16
            const int c4 = quad + 4 * w4;
#pragma unroll
            for (int s = 0; s < 4; ++s) {
                const int n = lo + 16 * s;
                const float* p = &xb[(size_t)(kc + c4 * 4) * NN + n0 + n];
                uint2 u;
                u.x = pk2(p[0], p[NN]);
                u.y = pk2(p[2 * NN], p[3 * NN]);
                *(uint2*)&Xs[n][c4 * 4] = u;
            }
        }
        __syncthreads();
        if (!isV) {
            bf16x8 a0 = *(const bf16x8*)&Wqb[(size_t)(o0 + 16 * w4 + lo) * CDIM + kc + quad * 8];
            bf16x8 a1 = *(const bf16x8*)&Wqb[(size_t)(o0 + 16 * w4 + lo) * CDIM + kc + 32 + quad * 8];
#pragma unroll
            for (int nt = 0; nt < 4; ++nt) {
                bf16x8 b0 = *(const bf16x8*)&Xs[nt * 16 + lo][quad * 8];
                bf16x8 b1 = *(const bf16x8*)&Xs[nt * 16 + lo][32 + quad * 8];
                acc[nt] = MFMA16(a0, b0, acc[nt]);
                acc[nt] = MFMA16(a1, b1, acc[nt]);
            }
        } else {
            bf16x8 a0 = *(const bf16x8*)&Xs[16 * w4 + lo][quad * 8];
            bf16x8 a1 = *(const bf16x8*)&Xs[16 * w4 + lo][32 + quad * 8];
#pragma unroll
            for (int ot = 0; ot < 4; ++ot) {
                bf16x8 b0 = *(const bf16x8*)&Wqb[(size_t)(o0 + ot * 16 + lo) * CDIM + kc + quad * 8];
                bf16x8 b1 = *(const bf16x8*)&Wqb[(size_t)(o0 + ot * 16 + lo) * CDIM + kc + 32 + quad * 8];
                acc[ot] = MFMA16(a0, b0, acc[ot]);
                acc[ot] = MFMA16(a1, b1, acc[ot]);
            }
        }
    }
    if (!isV) {
        const bool isK = (o0 >= HIDDEN);
        const int h = (isK ? (o0 - HIDDEN) : o0) >> 6;
        unsigned short* dst = isK ? Kb : Qb;
        const int c0 = 16 * w4 + quad * 4;           // rows o -> c, consecutive over reg r
#pragma unroll
        for (int nt = 0; nt < 4; ++nt) {
            const int n = n0 + nt * 16 + lo;
            uint2 u;
            u.x = pk2(acc[nt][0], acc[nt][1]);
            u.y = pk2(acc[nt][2], acc[nt][3]);
            *(uint2*)&dst[(((size_t)(b * HEADS + h)) * NN + n) * DH + c0] = u;
        }
    } else {
        const int h = (o0 - 2 * HIDDEN) >> 6;
        const int m0b = n0 + 16 * w4 + quad * 4;     // rows n -> m, consecutive over reg r
#pragma unroll
        for (int ot = 0; ot < 4; ++ot) {
            const int c = ot * 16 + lo;
            uint2 u;
            u.x = pk2(acc[ot][0], acc[ot][1]);
            u.y = pk2(acc[ot][2], acc[ot][3]);
            *(uint2*)&Vb[(((size_t)(b * HEADS + h)) * DH + c) * NN + m0b] = u;
        }
    }
}

// ---------------- Kernel B: MFMA flash attention (S^T form) ----------------
// S^T[m][q] = K·Q^T  (A = Ks[m][c], B = Q^T from global, both c-contig)
// => C-layout col = q = lane&15: softmax state is per-thread scalar.
// O^T[c][q] += V^T·P^T (A = Vs[c][m] natural, B = Ps[q][m] via LDS round-trip)
__global__ __launch_bounds__(256, 4) void flash_attn(const unsigned short* __restrict__ Qb,
                                                     const unsigned short* __restrict__ Kb,
                                                     const unsigned short* __restrict__ Vb,
                                                     unsigned short* __restrict__ Yb) {
    __shared__ unsigned short Ks[64][72], Vs[64][72], Ps[64][72];
    const int q0 = blockIdx.x * 64, h = blockIdx.y, b = blockIdx.z;
    const int t = threadIdx.x, l = t & 63, w = t >> 6, lo = l & 15, quad = l >> 4;
    const int bh = b * HEADS + h;
    const unsigned short* Qp = Qb + (size_t)bh * NN * DH;
    const unsigned short* Kp = Kb + (size_t)bh * NN * DH;
    const unsigned short* Vp = Vb + (size_t)bh * DH * NN;
    const int q = q0 + 16 * w + lo;
    const bf16x8 bQ0 = *(const bf16x8*)&Qp[(size_t)q * DH + quad * 8];
    const bf16x8 bQ1 = *(const bf16x8*)&Qp[(size_t)q * DH + 32 + quad * 8];
    f32x4 O[4];
#pragma unroll
    for (int i = 0; i < 4; ++i) O[i] = (f32x4){0.f, 0.f, 0.f, 0.f};
    float m_i = -INFINITY, l_i = 0.f;
    const int r_st = t >> 3, c_st = (t & 7) * 8;     // staging: 2 rows x 16B per thread

    for (int m0 = 0; m0 < NN; m0 += 64) {
        __syncthreads();
        {   // stage K (c-contig rows) and V (m-contig rows), pure bf16 copies
            const unsigned short* ksrc = Kp + (size_t)m0 * DH;
            *(uint4*)&Ks[r_st][c_st]      = *(const uint4*)&ksrc[(size_t)r_st * DH + c_st];
            *(uint4*)&Ks[r_st + 32][c_st] = *(const uint4*)&ksrc[(size_t)(r_st + 32) * DH + c_st];
            *(uint4*)&Vs[r_st][c_st]      = *(const uint4*)&Vp[(size_t)r_st * NN + m0 + c_st];
            *(uint4*)&Vs[r_st + 32][c_st] = *(const uint4*)&Vp[(size_t)(r_st + 32) * NN + m0 + c_st];
        }
        __syncthreads();
        // ---- S^T tiles: rows m = nt*16+quad*4+r, col q = 16w+lo ----
        f32x4 S[4];
#pragma unroll
        for (int nt = 0; nt < 4; ++nt) {
            bf16x8 a0 = *(const bf16x8*)&Ks[nt * 16 + lo][quad * 8];
            bf16x8 a1 = *(const bf16x8*)&Ks[nt * 16 + lo][32 + quad * 8];
            f32x4 z = (f32x4){0.f, 0.f, 0.f, 0.f};
            z = MFMA16(a0, bQ0, z);
            z = MFMA16(a1, bQ1, z);
            S[nt] = z;
        }
        // ---- online softmax over m: 16 local values + cross-quad (2 shuffles) ----
        float mx;
        {
            f32x4 mm;
#pragma unroll
            for (int i = 0; i < 4; ++i)
                mm[i] = fmaxf(fmaxf(S[0][i], S[1][i]), fmaxf(S[2][i], S[3][i]));
            mx = fmaxf(fmaxf(mm[0], mm[1]), fmaxf(mm[2], mm[3]));
        }
        mx = fmaxf(mx, __shfl_xor(mx, 16));
        mx = fmaxf(mx, __shfl_xor(mx, 32));
        const float mn = fmaxf(m_i, mx);
        const float alpha = EXP2(m_i - mn);
        m_i = mn;
        f32x4 Pv[4], sv = (f32x4){0.f, 0.f, 0.f, 0.f};
#pragma unroll
        for (int nt = 0; nt < 4; ++nt) {
#pragma unroll
            for (int i = 0; i < 4; ++i) Pv[nt][i] = EXP2(S[nt][i] - mn);
            sv += Pv[nt];
        }
        float ls = (sv[0] + sv[1]) + (sv[2] + sv[3]);
        ls += __shfl_xor(ls, 16);
        ls += __shfl_xor(ls, 32);
        l_i = l_i * alpha + ls;
        // ---- P to LDS: row q (wave-private), m-contiguous -> b64 writes ----
#pragma unroll
        for (int nt = 0; nt < 4; ++nt) {
            uint2 u;
            u.x = pk2(Pv[nt][0], Pv[nt][1]);
            u.y = pk2(Pv[nt][2], Pv[nt][3]);
            *(uint2*)&Ps[16 * w + lo][nt * 16 + quad * 4] = u;
        }
        asm volatile("s_waitcnt lgkmcnt(0)" ::: "memory");   // same-wave write->read drain
#pragma unroll
        for (int ct = 0; ct < 4; ++ct) O[ct] *= alpha;
        const bf16x8 pb0 = *(const bf16x8*)&Ps[16 * w + lo][quad * 8];
        const bf16x8 pb1 = *(const bf16x8*)&Ps[16 * w + lo][32 + quad * 8];
#pragma unroll
        for (int ct = 0; ct < 4; ++ct) {
            bf16x8 a0 = *(const bf16x8*)&Vs[ct * 16 + lo][quad * 8];
            bf16x8 a1 = *(const bf16x8*)&Vs[ct * 16 + lo][32 + quad * 8];
            O[ct] = MFMA16(a0, pb0, O[ct]);
            O[ct] = MFMA16(a1, pb1, O[ct]);
        }
    }
    const float inv = 1.f / l_i;
    unsigned short* yrow = Yb + (((size_t)(b * NN) + q)) * HIDDEN + h * DH;
#pragma unroll
    for (int ct = 0; ct < 4; ++ct) {   // O^T rows c = ct*16+quad*4+r -> contiguous bf16x4
        uint2 u;
        u.x = pk2(O[ct][0] * inv, O[ct][1] * inv);
        u.y = pk2(O[ct][2] * inv, O[ct][3] * inv);
        *(uint2*)&yrow[ct * 16 + quad * 4] = u;
    }
}

// ---------------- Kernel C: out projection, all-register (no LDS) ----------------
// D[n][o] = sum_k Y[n][k] * w_out[o][k] + bias; A and B frags direct from global bf16.
__global__ __launch_bounds__(256, 4) void out_gemm(const unsigned short* __restrict__ Yb,
                                                   const unsigned short* __restrict__ Wob,
                                                   const float* __restrict__ bias,
                                                   float* __restrict__ out) {
    const int n0 = blockIdx.x * 64, o0 = blockIdx.y * 64, b = blockIdx.z;
    const int t = threadIdx.x, l = t & 63, w4 = t >> 6, lo = l & 15, quad = l >> 4;
    f32x4 acc[4];
#pragma unroll
    for (int i = 0; i < 4; ++i) acc[i] = (f32x4){0.f, 0.f, 0.f, 0.f};
    const unsigned short* ya = Yb + ((size_t)(b * NN) + n0 + 16 * w4 + lo) * HIDDEN;
#pragma unroll 4
    for (int kc = 0; kc < HIDDEN; kc += 32) {
        bf16x8 a = *(const bf16x8*)&ya[kc + quad * 8];
#pragma unroll
        for (int ot = 0; ot < 4; ++ot) {
            bf16x8 bw = *(const bf16x8*)&Wob[(size_t)(o0 + ot * 16 + lo) * HIDDEN + kc + quad * 8];
            acc[ot] = MFMA16(a, bw, acc[ot]);
        }
    }
#pragma unroll
    for (int ot = 0; ot < 4; ++ot) {
        const int o = o0 + ot * 16 + lo;
        const float bv = bias[o];
        *(f32x4*)&out[((size_t)(b * CDIM) + o) * NN + n0 + 16 * w4 + quad * 4] = acc[ot] + bv;
    }
}

extern "C" void kernel_launch(void* const* d_in, const int* in_sizes, int n_in,
                              void* d_out, int out_size, void* d_ws, size_t ws_size,
                              hipStream_t stream) {
    const float* x     = (const float*)d_in[0];
    const float* w_qkv = (const float*)d_in[1];
    const float* w_out = (const float*)d_in[2];
    const float* b_out = (const float*)d_in[3];
    float* out = (float*)d_out;

    unsigned short* Wqb = (unsigned short*)d_ws;                  // 1536*256
    unsigned short* Wob = Wqb + (size_t)THREEH * CDIM;            // 256*512
    unsigned short* Qb  = Wob + (size_t)CDIM * HIDDEN;            // [b][h][n][c], pre-scaled
    unsigned short* Kb  = Qb + (size_t)BB * HEADS * NN * DH;      // [b][h][n][c]
    unsigned short* Vb  = Kb + (size_t)BB * HEADS * NN * DH;      // [b][h][c][n]
    unsigned short* Yb  = Vb + (size_t)BB * HEADS * DH * NN;      // [b][n][hidden]

    prep_w<<<512, 256, 0, stream>>>(w_qkv, w_out, (unsigned*)Wqb, (unsigned*)Wob);
    qkv_gemm<<<dim3(NN / 64, THREEH / 64, BB), 256, 0, stream>>>(x, Wqb, Qb, Kb, Vb);
    flash_attn<<<dim3(NN / 64, HEADS, BB), 256, 0, stream>>>(Qb, Kb, Vb, Yb);
    out_gemm<<<dim3(NN / 64, CDIM / 64, BB), 256, 0, stream>>>(Yb, Wob, b_out, out);
}